// Round 2
// baseline (265.592 us; speedup 1.0000x reference)
//
#include <hip/hip_runtime.h>
#include <math.h>

// DVGO volume-rendering forward, round 11.
// r10 null (instrs halved, occupancy up, time flat) kills instruction-issue
// and MLP theories. Remaining model: unique-L1-miss-line traffic x L2 latency
// under a capped per-CU miss budget. This round cuts unique lines by layout:
//   - SPLIT records: GridA = [dens|off0|off1|off2] 4B, GridB = [emo0..2|pad]
//     4B. Off-rays (~50%) read only GridA -> half the tube bytes/lines.
//   - BRICK 2x2x4 voxels x 4B = exactly one 64B line -> isotropic ~27-line
//     tube per chunk vs 60-100 (direction-dependent) row-major.
// Gathers become 8 (off) / 16 (on) scalar dword loads + ~40 VALU of brick
// indexing per sample; both proven non-binding. Repack rewritten brick-wise
// (thread=brick: coalesced float4 reads, full 64B line writes).
// Predicted: dvgo 57.5 -> ~35-40 us, FETCH 83 -> ~60-70 MB, VALUBusy ~30%.
// If flat again with FETCH down: model wrong, pivot to cross-chunk pipelining.

namespace {
constexpr int   kR   = 8192;
constexpr int   kS   = 558;
constexpr int   kG   = 160;
constexpr int   kG3  = kG * kG * kG;
constexpr float kNear = 0.05f;
constexpr float kFar  = 6.0f;
constexpr float kStepWorld = 0.5f * (2.0f / 160.0f);  // STEPSIZE * VOXEL_SIZE
constexpr float kActShift = -13.815509557963774f;     // log(1/(1-1e-6)-1)
constexpr float kLog2e = 1.4426950408889634f;
// brick layout: 2x2x4 voxels, 16 records x 4B = 64B = one cache line
constexpr int   kBX = 80, kBY = 80, kBZ = 40;
constexpr int   kNB = kBX * kBY * kBZ;            // 256000 bricks
constexpr int   kGridWords = kNB * 16;            // 4,096,000 words = 16.4 MB
}

typedef unsigned int nuint4 __attribute__((ext_vector_type(4)));
typedef float        nfloat2 __attribute__((ext_vector_type(2)));
typedef float        nfloat4 __attribute__((ext_vector_type(4)));

__device__ __forceinline__ float fexp(float x) {   // e^x
  return __builtin_amdgcn_exp2f(x * kLog2e);
}
__device__ __forceinline__ float sigmoidf_(float x) {
  return __builtin_amdgcn_rcpf(1.0f + fexp(-x));
}

// ---- repack: planar 7-channel f32 -> two bricked fp8 grids ----
// thread = one 2x2x4 brick; reads 7 channels x 4 rows as float4 (coalesced
// along bz), writes one full 64B line per grid.
__global__ __launch_bounds__(256) void repack_grids(
    const float* __restrict__ density,
    const float* __restrict__ off_c,
    const float* __restrict__ emo_c,
    unsigned* __restrict__ gridA,    // [kNB*16] dens|off0|off1|off2
    unsigned* __restrict__ gridB)    // [kNB*16] emo0|emo1|emo2|0
{
  const int bid = blockIdx.x * blockDim.x + threadIdx.x;
  if (bid >= kNB) return;
  const int bz = bid % kBZ;
  const int t  = bid / kBZ;
  const int by = t % kBY;
  const int bx = t / kBY;
  const int x0 = bx * 2, y0 = by * 2, z0 = bz * 4;

  unsigned wa[16], wb[16];
  #pragma unroll
  for (int lx = 0; lx < 2; ++lx) {
    #pragma unroll
    for (int ly = 0; ly < 2; ++ly) {
      const int vbase = ((x0 + lx) * kG + (y0 + ly)) * kG + z0;
      const nfloat4 d  = *(const nfloat4*)(density + vbase);
      const nfloat4 f0 = *(const nfloat4*)(off_c + vbase);
      const nfloat4 f1 = *(const nfloat4*)(off_c + vbase + kG3);
      const nfloat4 f2 = *(const nfloat4*)(off_c + vbase + 2 * kG3);
      const nfloat4 e0 = *(const nfloat4*)(emo_c + vbase);
      const nfloat4 e1 = *(const nfloat4*)(emo_c + vbase + kG3);
      const nfloat4 e2 = *(const nfloat4*)(emo_c + vbase + 2 * kG3);
      #pragma unroll
      for (int lz = 0; lz < 4; ++lz) {
        const int s = (lx * 2 + ly) * 4 + lz;
        int qa = __builtin_amdgcn_cvt_pk_fp8_f32(d[lz],  f0[lz], 0,  false);
        qa     = __builtin_amdgcn_cvt_pk_fp8_f32(f1[lz], f2[lz], qa, true);
        int qb = __builtin_amdgcn_cvt_pk_fp8_f32(e0[lz], e1[lz], 0,  false);
        qb     = __builtin_amdgcn_cvt_pk_fp8_f32(e2[lz], 0.0f,   qb, true);
        wa[s] = (unsigned)qa;
        wb[s] = (unsigned)qb;
      }
    }
  }
  nuint4* oa = (nuint4*)(gridA + (size_t)bid * 16);
  nuint4* ob = (nuint4*)(gridB + (size_t)bid * 16);
  #pragma unroll
  for (int q = 0; q < 4; ++q) {
    nuint4 va; va.x = wa[4*q]; va.y = wa[4*q+1]; va.z = wa[4*q+2]; va.w = wa[4*q+3];
    nuint4 vb; vb.x = wb[4*q]; vb.y = wb[4*q+1]; vb.z = wb[4*q+2]; vb.w = wb[4*q+3];
    __builtin_nontemporal_store(va, oa + q);
    __builtin_nontemporal_store(vb, ob + q);
  }
}

__device__ __forceinline__ int brick_widx(int gx, int gy, int gz) {
  return (((gx >> 1) * kBY + (gy >> 1)) * kBZ + (gz >> 2)) * 16 +
         ((gx & 1) * 2 + (gy & 1)) * 4 + (gz & 3);
}

// ---- main: one 64-lane wave per ray (fused) ----
__global__ __launch_bounds__(256) void dvgo_fwd(
    const float* __restrict__ rays_o,
    const float* __restrict__ rays_d,
    const float* __restrict__ jitter,
    const int*   __restrict__ em_modes,
    const unsigned* __restrict__ gridA,
    const unsigned* __restrict__ gridB,
    float* __restrict__ out)
{
  const int tid  = blockIdx.x * blockDim.x + threadIdx.x;
  const int ray  = tid >> 6;
  const int lane = tid & 63;
  if (ray >= kR) return;

  const float ox = rays_o[ray * 3 + 0];
  const float oy = rays_o[ray * 3 + 1];
  const float oz = rays_o[ray * 3 + 2];
  const float dx = rays_d[ray * 3 + 0];
  const float dy = rays_d[ray * 3 + 1];
  const float dz = rays_d[ray * 3 + 2];
  const float jit = jitter[ray];
  const bool  on  = (em_modes[ray] == 1);

  const float vx = (dx == 0.0f) ? 1e-6f : dx;
  const float vy = (dy == 0.0f) ? 1e-6f : dy;
  const float vz = (dz == 0.0f) ? 1e-6f : dz;
  const float ivx = __builtin_amdgcn_rcpf(vx);
  const float ivy = __builtin_amdgcn_rcpf(vy);
  const float ivz = __builtin_amdgcn_rcpf(vz);
  const float rax = ( 1.0f - ox) * ivx, rbx = (-1.0f - ox) * ivx;
  const float ray_a = ( 1.0f - oy) * ivy, rby = (-1.0f - oy) * ivy;
  const float raz = ( 1.0f - oz) * ivz, rbz = (-1.0f - oz) * ivz;
  float tmin = fmaxf(fmaxf(fminf(rax, rbx), fminf(ray_a, rby)), fminf(raz, rbz));
  float tmax = fminf(fminf(fmaxf(rax, rbx), fmaxf(ray_a, rby)), fmaxf(raz, rbz));
  tmin = fminf(fmaxf(tmin, kNear), kFar);
  tmax = fminf(fmaxf(tmax, kNear), kFar);
  const bool  ray_out = (tmax <= tmin);
  const float stepc = kStepWorld *
      __builtin_amdgcn_rsqf(dx * dx + dy * dy + dz * dz);

  float* out_ainv = out;                           // [R, S+1]
  float* out_w    = out + (size_t)kR * (kS + 1);   // [R, S]
  float* out_last = out_w + (size_t)kR * kS;       // [R, 1]
  float* out_rgb  = out_last + kR;                 // [R, S, 3]
  float* out_rm   = out_rgb + (size_t)kR * kS * 3; // [R, 3]

  if (lane == 0)
    __builtin_nontemporal_store(1.0f, out_ainv + (size_t)ray * (kS + 1));

  const float c_base = on ? 1.0f : 0.5f;  // sigma(0) (+sigma(0) if on)

  float carry = 1.0f;
  float accr = 0.0f, accg = 0.0f, accb = 0.0f;
  bool dead = false;

  #pragma unroll 1
  for (int chunk = 0; chunk < (kS + 63) / 64; ++chunk) {
    const int  s      = chunk * 64 + lane;
    const bool active = (s < kS);

    if (!dead) {
      const float t  = tmin + stepc * ((float)s + jit);
      const float px = fmaf(dx, t, ox);
      const float py = fmaf(dy, t, oy);
      const float pz = fmaf(dz, t, oz);
      const bool inb = (px >= -1.0f) & (px <= 1.0f) &
                       (py >= -1.0f) & (py <= 1.0f) &
                       (pz >= -1.0f) & (pz <= 1.0f);
      const bool masked = ray_out || !inb;

      const float fx = (px + 1.0f) * 0.5f * (float)(kG - 1);
      const float fy = (py + 1.0f) * 0.5f * (float)(kG - 1);
      const float fz = (pz + 1.0f) * 0.5f * (float)(kG - 1);
      const int ix = (int)floorf(fx);
      const int iy = (int)floorf(fy);
      const int iz = (int)floorf(fz);

      const bool reach = active &&
          (ix >= -1) && (ix <= kG - 1) &&
          (iy >= -1) && (iy <= kG - 1) &&
          (iz >= -1) && (iz <= kG - 1);
      if (__ballot(reach) == 0ull) {
        dead = true;  // monotone: no later sample re-enters reach
      } else {
        const float wx = fx - (float)ix;
        const float wy = fy - (float)iy;
        const float wz = fz - (float)iz;
        const float x0 = 1.0f - wx, y0 = 1.0f - wy, z0 = 1.0f - wz;
        const float wxy00 = x0 * y0, wxy01 = x0 * wy;
        const float wxy10 = wx * y0, wxy11 = wx * wy;
        float w8[8];
        w8[0] = wxy00 * z0; w8[1] = wxy00 * wz;
        w8[2] = wxy01 * z0; w8[3] = wxy01 * wz;
        w8[4] = wxy10 * z0; w8[5] = wxy10 * wz;
        w8[6] = wxy11 * z0; w8[7] = wxy11 * wz;

        float dsum = 0.0f;
        float o0 = 0.0f, o1 = 0.0f, o2 = 0.0f;
        float e0 = 0.0f, e1 = 0.0f, e2 = 0.0f;

        const bool interior = active &&
            (ix >= 0) && (ix < kG - 1) &&
            (iy >= 0) && (iy < kG - 1) &&
            (iz >= 0) && (iz < kG - 1);

        if (interior) {
          // brick decomposition of the 2x2x2 footprint, shared subterms
          const int bx = ix >> 1, lx = ix & 1;
          const int by = iy >> 1, ly = iy & 1;
          const int bz = iz >> 2, lz = iz & 3;
          const int bz1 = (iz + 1) >> 2, lz1 = (iz + 1) & 3;
          const int r00 = (bx * kBY + by) * kBZ;
          const int r10 = r00 + lx * (kBY * kBZ);   // x-corner 1 row
          const int r01 = r00 + ly * kBZ;           // y-corner 1 row
          const int r11 = r10 + ly * kBZ;
          const int sx0 = (lx) * 2,      sx1 = (lx ^ 1) * 2;
          const int sy0 = ly,            sy1 = ly ^ 1;
          int widx[8];
          widx[0] = (r00 + bz ) * 16 + (sx0 + sy0) * 4 + lz;
          widx[1] = (r00 + bz1) * 16 + (sx0 + sy0) * 4 + lz1;
          widx[2] = (r01 + bz ) * 16 + (sx0 + sy1) * 4 + lz;
          widx[3] = (r01 + bz1) * 16 + (sx0 + sy1) * 4 + lz1;
          widx[4] = (r10 + bz ) * 16 + (sx1 + sy0) * 4 + lz;
          widx[5] = (r10 + bz1) * 16 + (sx1 + sy0) * 4 + lz1;
          widx[6] = (r11 + bz ) * 16 + (sx1 + sy1) * 4 + lz;
          widx[7] = (r11 + bz1) * 16 + (sx1 + sy1) * 4 + lz1;

          unsigned ua[8];
          #pragma unroll
          for (int c = 0; c < 8; ++c) ua[c] = gridA[widx[c]];
          if (on) {
            unsigned ub[8];
            #pragma unroll
            for (int c = 0; c < 8; ++c) ub[c] = gridB[widx[c]];
            #pragma unroll
            for (int c = 0; c < 8; ++c) {
              const float w = w8[c];
              dsum = fmaf(w, __builtin_amdgcn_cvt_f32_fp8((int)ua[c], 0), dsum);
              o0   = fmaf(w, __builtin_amdgcn_cvt_f32_fp8((int)ua[c], 1), o0);
              o1   = fmaf(w, __builtin_amdgcn_cvt_f32_fp8((int)ua[c], 2), o1);
              o2   = fmaf(w, __builtin_amdgcn_cvt_f32_fp8((int)ua[c], 3), o2);
              e0   = fmaf(w, __builtin_amdgcn_cvt_f32_fp8((int)ub[c], 0), e0);
              e1   = fmaf(w, __builtin_amdgcn_cvt_f32_fp8((int)ub[c], 1), e1);
              e2   = fmaf(w, __builtin_amdgcn_cvt_f32_fp8((int)ub[c], 2), e2);
            }
          } else {
            #pragma unroll
            for (int c = 0; c < 8; ++c) {
              const float w = w8[c];
              dsum = fmaf(w, __builtin_amdgcn_cvt_f32_fp8((int)ua[c], 0), dsum);
              o0   = fmaf(w, __builtin_amdgcn_cvt_f32_fp8((int)ua[c], 1), o0);
              o1   = fmaf(w, __builtin_amdgcn_cvt_f32_fp8((int)ua[c], 2), o1);
              o2   = fmaf(w, __builtin_amdgcn_cvt_f32_fp8((int)ua[c], 3), o2);
            }
          }
        } else if (reach) {
          #pragma unroll
          for (int c = 0; c < 8; ++c) {
            const int cx = ix + ((c >> 2) & 1);
            const int cy = iy + ((c >> 1) & 1);
            const int cz = iz + (c & 1);
            const bool valid = ((unsigned)cx < (unsigned)kG) &
                               ((unsigned)cy < (unsigned)kG) &
                               ((unsigned)cz < (unsigned)kG);
            const float wv = valid ? w8[c] : 0.0f;
            const int gx = min(max(cx, 0), kG - 1);
            const int gy = min(max(cy, 0), kG - 1);
            const int gz = min(max(cz, 0), kG - 1);
            const int wi = brick_widx(gx, gy, gz);
            const unsigned qa = gridA[wi];
            dsum = fmaf(wv, __builtin_amdgcn_cvt_f32_fp8((int)qa, 0), dsum);
            o0   = fmaf(wv, __builtin_amdgcn_cvt_f32_fp8((int)qa, 1), o0);
            o1   = fmaf(wv, __builtin_amdgcn_cvt_f32_fp8((int)qa, 2), o1);
            o2   = fmaf(wv, __builtin_amdgcn_cvt_f32_fp8((int)qa, 3), o2);
            if (on) {
              const unsigned qb = gridB[wi];
              e0 = fmaf(wv, __builtin_amdgcn_cvt_f32_fp8((int)qb, 0), e0);
              e1 = fmaf(wv, __builtin_amdgcn_cvt_f32_fp8((int)qb, 1), e1);
              e2 = fmaf(wv, __builtin_amdgcn_cvt_f32_fp8((int)qb, 2), e2);
            }
          }
        }

        // p = (1+e^x)^-0.5 == exp(-softplus(x)*0.5) exactly; masked -> 1
        float p = 1.0f;
        if (active && !masked) {
          const float ex = fexp(dsum + kActShift);
          p = fmaxf(__builtin_amdgcn_rsqf(1.0f + ex), 1e-10f);
        }
        const float alpha = 1.0f - p;

        float incl = p;
        #pragma unroll
        for (int o = 1; o < 64; o <<= 1) {
          const float n = __shfl_up(incl, o, 64);
          if (lane >= o) incl *= n;
        }
        float excl = __shfl_up(incl, 1, 64);
        if (lane == 0) excl = 1.0f;
        const float ainv_prev = carry * excl;
        const float ainv_next = carry * incl;
        const float wgt = alpha * ainv_prev;
        carry *= __shfl(incl, 63, 64);

        float rr = sigmoidf_(o0);
        float gg = sigmoidf_(o1);
        float bb = sigmoidf_(o2);
        if (on) {
          rr += sigmoidf_(e0);
          gg += sigmoidf_(e1);
          bb += sigmoidf_(e2);
        }

        if (active) {
          __builtin_nontemporal_store(ainv_next,
              out_ainv + (size_t)ray * (kS + 1) + s + 1);
          __builtin_nontemporal_store(wgt, out_w + (size_t)ray * kS + s);
          const size_t rb = ((size_t)ray * kS + s) * 3;
          nfloat2 rg;
          rg.x = rr; rg.y = gg;
          __builtin_nontemporal_store(rg, (nfloat2*)(out_rgb + rb));
          __builtin_nontemporal_store(bb, out_rgb + rb + 2);
          accr = fmaf(wgt, rr, accr);
          accg = fmaf(wgt, gg, accg);
          accb = fmaf(wgt, bb, accb);
        }
        continue;  // live chunk handled
      }
    }

    // dead tail: alpha=0, p=1, sampler output 0 -> rgb consts
    if (active) {
      __builtin_nontemporal_store(carry,
          out_ainv + (size_t)ray * (kS + 1) + s + 1);
      __builtin_nontemporal_store(0.0f, out_w + (size_t)ray * kS + s);
      const size_t rb = ((size_t)ray * kS + s) * 3;
      nfloat2 cb;
      cb.x = c_base; cb.y = c_base;
      __builtin_nontemporal_store(cb, (nfloat2*)(out_rgb + rb));
      __builtin_nontemporal_store(c_base, out_rgb + rb + 2);
    }
  }

  #pragma unroll
  for (int o = 32; o > 0; o >>= 1) {
    accr += __shfl_xor(accr, o, 64);
    accg += __shfl_xor(accg, o, 64);
    accb += __shfl_xor(accb, o, 64);
  }
  if (lane == 0) {
    out_last[ray] = carry;
    out_rm[(size_t)ray * 3 + 0] = accr;
    out_rm[(size_t)ray * 3 + 1] = accg;
    out_rm[(size_t)ray * 3 + 2] = accb;
  }
}

extern "C" void kernel_launch(void* const* d_in, const int* in_sizes, int n_in,
                              void* d_out, int out_size, void* d_ws, size_t ws_size,
                              hipStream_t stream) {
  const float* rays_o  = (const float*)d_in[0];
  const float* rays_d  = (const float*)d_in[1];
  const float* jitter  = (const float*)d_in[2];
  const int*   em      = (const int*)d_in[3];
  const float* density = (const float*)d_in[4];
  const float* off_c   = (const float*)d_in[5];
  const float* emo_c   = (const float*)d_in[6];
  float* out = (float*)d_out;

  unsigned* gridA = (unsigned*)d_ws;          // 16.4 MB
  unsigned* gridB = gridA + kGridWords;       // 16.4 MB
  (void)ws_size;

  hipLaunchKernelGGL(repack_grids, dim3((kNB + 255) / 256), dim3(256), 0,
                     stream, density, off_c, emo_c, gridA, gridB);

  const int threads = 256;
  const int blocks  = (kR * 64) / threads;  // 2048
  hipLaunchKernelGGL(dvgo_fwd, dim3(blocks), dim3(threads), 0, stream,
                     rays_o, rays_d, jitter, em, gridA, gridB, out);
}

// Round 3
// 225.492 us; speedup vs baseline: 1.1778x; 1.1778x over previous
//
#include <hip/hip_runtime.h>
#include <math.h>

// DVGO volume-rendering forward, round 12.
// r11 post-mortem: bricking+split WORKED for dvgo_fwd (57.5 -> ~28 us,
// backed out of harness total), but the thread=brick repack regressed to
// 76.5 us (VALUBusy 1.8%: wa[16]/wb[16] arrays + 28 in-flight loads ->
// 32-VGPR serialized schedule, no ILP). This round fixes ONLY repack:
//   thread = brick QUARTER (4 threads/brick). Quarter q = sub-block
//   (lx,ly)=(q>>1,q&1) = exactly one float4 per channel read and one
//   nuint4 per grid write. 7 loads + 2 stores, no arrays, no loops.
//   Reads: 4x256B contiguous clusters/wave; writes: 1024B contiguous/wave.
// dvgo_fwd byte-identical to r11.
// Predicted: repack 76.5 -> ~25-30 us (memory floor: 114.7 MB read +
// 65.5 MB write), VALUBusy ~10%, hbm ~5.5-6 TB/s; dvgo unchanged ~28 us;
// harness 265.6 -> ~165 us.

namespace {
constexpr int   kR   = 8192;
constexpr int   kS   = 558;
constexpr int   kG   = 160;
constexpr int   kG3  = kG * kG * kG;
constexpr float kNear = 0.05f;
constexpr float kFar  = 6.0f;
constexpr float kStepWorld = 0.5f * (2.0f / 160.0f);  // STEPSIZE * VOXEL_SIZE
constexpr float kActShift = -13.815509557963774f;     // log(1/(1-1e-6)-1)
constexpr float kLog2e = 1.4426950408889634f;
// brick layout: 2x2x4 voxels, 16 records x 4B = 64B = one cache line
constexpr int   kBX = 80, kBY = 80, kBZ = 40;
constexpr int   kNB = kBX * kBY * kBZ;            // 256000 bricks
constexpr int   kGridWords = kNB * 16;            // 4,096,000 words = 16.4 MB
}

typedef unsigned int nuint4 __attribute__((ext_vector_type(4)));
typedef float        nfloat2 __attribute__((ext_vector_type(2)));
typedef float        nfloat4 __attribute__((ext_vector_type(4)));

__device__ __forceinline__ float fexp(float x) {   // e^x
  return __builtin_amdgcn_exp2f(x * kLog2e);
}
__device__ __forceinline__ float sigmoidf_(float x) {
  return __builtin_amdgcn_rcpf(1.0f + fexp(-x));
}

// ---- repack: planar 7-channel f32 -> two bricked fp8 grids ----
// thread = one brick QUARTER: sub-block (lx,ly) = (q>>1, q&1), 4 voxels
// along z. One float4 read per channel, one nuint4 write per grid.
__global__ __launch_bounds__(256) void repack_grids(
    const float* __restrict__ density,
    const float* __restrict__ off_c,
    const float* __restrict__ emo_c,
    unsigned* __restrict__ gridA,    // [kNB*16] dens|off0|off1|off2
    unsigned* __restrict__ gridB)    // [kNB*16] emo0|emo1|emo2|0
{
  const int t   = blockIdx.x * blockDim.x + threadIdx.x;
  const int bid = t >> 2;
  const int q   = t & 3;
  if (bid >= kNB) return;
  const int bz = bid % kBZ;
  const int u  = bid / kBZ;
  const int by = u % kBY;
  const int bx = u / kBY;
  const int x  = bx * 2 + (q >> 1);
  const int y  = by * 2 + (q & 1);
  const int z0 = bz * 4;
  const int vbase = (x * kG + y) * kG + z0;

  const nfloat4 d  = __builtin_nontemporal_load((const nfloat4*)(density + vbase));
  const nfloat4 f0 = __builtin_nontemporal_load((const nfloat4*)(off_c + vbase));
  const nfloat4 f1 = __builtin_nontemporal_load((const nfloat4*)(off_c + vbase + kG3));
  const nfloat4 f2 = __builtin_nontemporal_load((const nfloat4*)(off_c + vbase + 2 * kG3));
  const nfloat4 e0 = __builtin_nontemporal_load((const nfloat4*)(emo_c + vbase));
  const nfloat4 e1 = __builtin_nontemporal_load((const nfloat4*)(emo_c + vbase + kG3));
  const nfloat4 e2 = __builtin_nontemporal_load((const nfloat4*)(emo_c + vbase + 2 * kG3));

  nuint4 va, vb;
  #pragma unroll
  for (int lz = 0; lz < 4; ++lz) {
    int qa = __builtin_amdgcn_cvt_pk_fp8_f32(d[lz],  f0[lz], 0,  false);
    qa     = __builtin_amdgcn_cvt_pk_fp8_f32(f1[lz], f2[lz], qa, true);
    int qb = __builtin_amdgcn_cvt_pk_fp8_f32(e0[lz], e1[lz], 0,  false);
    qb     = __builtin_amdgcn_cvt_pk_fp8_f32(e2[lz], 0.0f,   qb, true);
    va[lz] = (unsigned)qa;
    vb[lz] = (unsigned)qb;
  }
  const size_t woff = (size_t)bid * 16 + q * 4;
  __builtin_nontemporal_store(va, (nuint4*)(gridA + woff));
  __builtin_nontemporal_store(vb, (nuint4*)(gridB + woff));
}

__device__ __forceinline__ int brick_widx(int gx, int gy, int gz) {
  return (((gx >> 1) * kBY + (gy >> 1)) * kBZ + (gz >> 2)) * 16 +
         ((gx & 1) * 2 + (gy & 1)) * 4 + (gz & 3);
}

// ---- main: one 64-lane wave per ray (fused) ----
__global__ __launch_bounds__(256) void dvgo_fwd(
    const float* __restrict__ rays_o,
    const float* __restrict__ rays_d,
    const float* __restrict__ jitter,
    const int*   __restrict__ em_modes,
    const unsigned* __restrict__ gridA,
    const unsigned* __restrict__ gridB,
    float* __restrict__ out)
{
  const int tid  = blockIdx.x * blockDim.x + threadIdx.x;
  const int ray  = tid >> 6;
  const int lane = tid & 63;
  if (ray >= kR) return;

  const float ox = rays_o[ray * 3 + 0];
  const float oy = rays_o[ray * 3 + 1];
  const float oz = rays_o[ray * 3 + 2];
  const float dx = rays_d[ray * 3 + 0];
  const float dy = rays_d[ray * 3 + 1];
  const float dz = rays_d[ray * 3 + 2];
  const float jit = jitter[ray];
  const bool  on  = (em_modes[ray] == 1);

  const float vx = (dx == 0.0f) ? 1e-6f : dx;
  const float vy = (dy == 0.0f) ? 1e-6f : dy;
  const float vz = (dz == 0.0f) ? 1e-6f : dz;
  const float ivx = __builtin_amdgcn_rcpf(vx);
  const float ivy = __builtin_amdgcn_rcpf(vy);
  const float ivz = __builtin_amdgcn_rcpf(vz);
  const float rax = ( 1.0f - ox) * ivx, rbx = (-1.0f - ox) * ivx;
  const float ray_a = ( 1.0f - oy) * ivy, rby = (-1.0f - oy) * ivy;
  const float raz = ( 1.0f - oz) * ivz, rbz = (-1.0f - oz) * ivz;
  float tmin = fmaxf(fmaxf(fminf(rax, rbx), fminf(ray_a, rby)), fminf(raz, rbz));
  float tmax = fminf(fminf(fmaxf(rax, rbx), fmaxf(ray_a, rby)), fmaxf(raz, rbz));
  tmin = fminf(fmaxf(tmin, kNear), kFar);
  tmax = fminf(fmaxf(tmax, kNear), kFar);
  const bool  ray_out = (tmax <= tmin);
  const float stepc = kStepWorld *
      __builtin_amdgcn_rsqf(dx * dx + dy * dy + dz * dz);

  float* out_ainv = out;                           // [R, S+1]
  float* out_w    = out + (size_t)kR * (kS + 1);   // [R, S]
  float* out_last = out_w + (size_t)kR * kS;       // [R, 1]
  float* out_rgb  = out_last + kR;                 // [R, S, 3]
  float* out_rm   = out_rgb + (size_t)kR * kS * 3; // [R, 3]

  if (lane == 0)
    __builtin_nontemporal_store(1.0f, out_ainv + (size_t)ray * (kS + 1));

  const float c_base = on ? 1.0f : 0.5f;  // sigma(0) (+sigma(0) if on)

  float carry = 1.0f;
  float accr = 0.0f, accg = 0.0f, accb = 0.0f;
  bool dead = false;

  #pragma unroll 1
  for (int chunk = 0; chunk < (kS + 63) / 64; ++chunk) {
    const int  s      = chunk * 64 + lane;
    const bool active = (s < kS);

    if (!dead) {
      const float t  = tmin + stepc * ((float)s + jit);
      const float px = fmaf(dx, t, ox);
      const float py = fmaf(dy, t, oy);
      const float pz = fmaf(dz, t, oz);
      const bool inb = (px >= -1.0f) & (px <= 1.0f) &
                       (py >= -1.0f) & (py <= 1.0f) &
                       (pz >= -1.0f) & (pz <= 1.0f);
      const bool masked = ray_out || !inb;

      const float fx = (px + 1.0f) * 0.5f * (float)(kG - 1);
      const float fy = (py + 1.0f) * 0.5f * (float)(kG - 1);
      const float fz = (pz + 1.0f) * 0.5f * (float)(kG - 1);
      const int ix = (int)floorf(fx);
      const int iy = (int)floorf(fy);
      const int iz = (int)floorf(fz);

      const bool reach = active &&
          (ix >= -1) && (ix <= kG - 1) &&
          (iy >= -1) && (iy <= kG - 1) &&
          (iz >= -1) && (iz <= kG - 1);
      if (__ballot(reach) == 0ull) {
        dead = true;  // monotone: no later sample re-enters reach
      } else {
        const float wx = fx - (float)ix;
        const float wy = fy - (float)iy;
        const float wz = fz - (float)iz;
        const float x0 = 1.0f - wx, y0 = 1.0f - wy, z0 = 1.0f - wz;
        const float wxy00 = x0 * y0, wxy01 = x0 * wy;
        const float wxy10 = wx * y0, wxy11 = wx * wy;
        float w8[8];
        w8[0] = wxy00 * z0; w8[1] = wxy00 * wz;
        w8[2] = wxy01 * z0; w8[3] = wxy01 * wz;
        w8[4] = wxy10 * z0; w8[5] = wxy10 * wz;
        w8[6] = wxy11 * z0; w8[7] = wxy11 * wz;

        float dsum = 0.0f;
        float o0 = 0.0f, o1 = 0.0f, o2 = 0.0f;
        float e0 = 0.0f, e1 = 0.0f, e2 = 0.0f;

        const bool interior = active &&
            (ix >= 0) && (ix < kG - 1) &&
            (iy >= 0) && (iy < kG - 1) &&
            (iz >= 0) && (iz < kG - 1);

        if (interior) {
          // brick decomposition of the 2x2x2 footprint, shared subterms
          const int bx = ix >> 1, lx = ix & 1;
          const int by = iy >> 1, ly = iy & 1;
          const int bz = iz >> 2, lz = iz & 3;
          const int bz1 = (iz + 1) >> 2, lz1 = (iz + 1) & 3;
          const int r00 = (bx * kBY + by) * kBZ;
          const int r10 = r00 + lx * (kBY * kBZ);   // x-corner 1 row
          const int r01 = r00 + ly * kBZ;           // y-corner 1 row
          const int r11 = r10 + ly * kBZ;
          const int sx0 = (lx) * 2,      sx1 = (lx ^ 1) * 2;
          const int sy0 = ly,            sy1 = ly ^ 1;
          int widx[8];
          widx[0] = (r00 + bz ) * 16 + (sx0 + sy0) * 4 + lz;
          widx[1] = (r00 + bz1) * 16 + (sx0 + sy0) * 4 + lz1;
          widx[2] = (r01 + bz ) * 16 + (sx0 + sy1) * 4 + lz;
          widx[3] = (r01 + bz1) * 16 + (sx0 + sy1) * 4 + lz1;
          widx[4] = (r10 + bz ) * 16 + (sx1 + sy0) * 4 + lz;
          widx[5] = (r10 + bz1) * 16 + (sx1 + sy0) * 4 + lz1;
          widx[6] = (r11 + bz ) * 16 + (sx1 + sy1) * 4 + lz;
          widx[7] = (r11 + bz1) * 16 + (sx1 + sy1) * 4 + lz1;

          unsigned ua[8];
          #pragma unroll
          for (int c = 0; c < 8; ++c) ua[c] = gridA[widx[c]];
          if (on) {
            unsigned ub[8];
            #pragma unroll
            for (int c = 0; c < 8; ++c) ub[c] = gridB[widx[c]];
            #pragma unroll
            for (int c = 0; c < 8; ++c) {
              const float w = w8[c];
              dsum = fmaf(w, __builtin_amdgcn_cvt_f32_fp8((int)ua[c], 0), dsum);
              o0   = fmaf(w, __builtin_amdgcn_cvt_f32_fp8((int)ua[c], 1), o0);
              o1   = fmaf(w, __builtin_amdgcn_cvt_f32_fp8((int)ua[c], 2), o1);
              o2   = fmaf(w, __builtin_amdgcn_cvt_f32_fp8((int)ua[c], 3), o2);
              e0   = fmaf(w, __builtin_amdgcn_cvt_f32_fp8((int)ub[c], 0), e0);
              e1   = fmaf(w, __builtin_amdgcn_cvt_f32_fp8((int)ub[c], 1), e1);
              e2   = fmaf(w, __builtin_amdgcn_cvt_f32_fp8((int)ub[c], 2), e2);
            }
          } else {
            #pragma unroll
            for (int c = 0; c < 8; ++c) {
              const float w = w8[c];
              dsum = fmaf(w, __builtin_amdgcn_cvt_f32_fp8((int)ua[c], 0), dsum);
              o0   = fmaf(w, __builtin_amdgcn_cvt_f32_fp8((int)ua[c], 1), o0);
              o1   = fmaf(w, __builtin_amdgcn_cvt_f32_fp8((int)ua[c], 2), o1);
              o2   = fmaf(w, __builtin_amdgcn_cvt_f32_fp8((int)ua[c], 3), o2);
            }
          }
        } else if (reach) {
          #pragma unroll
          for (int c = 0; c < 8; ++c) {
            const int cx = ix + ((c >> 2) & 1);
            const int cy = iy + ((c >> 1) & 1);
            const int cz = iz + (c & 1);
            const bool valid = ((unsigned)cx < (unsigned)kG) &
                               ((unsigned)cy < (unsigned)kG) &
                               ((unsigned)cz < (unsigned)kG);
            const float wv = valid ? w8[c] : 0.0f;
            const int gx = min(max(cx, 0), kG - 1);
            const int gy = min(max(cy, 0), kG - 1);
            const int gz = min(max(cz, 0), kG - 1);
            const int wi = brick_widx(gx, gy, gz);
            const unsigned qa = gridA[wi];
            dsum = fmaf(wv, __builtin_amdgcn_cvt_f32_fp8((int)qa, 0), dsum);
            o0   = fmaf(wv, __builtin_amdgcn_cvt_f32_fp8((int)qa, 1), o0);
            o1   = fmaf(wv, __builtin_amdgcn_cvt_f32_fp8((int)qa, 2), o1);
            o2   = fmaf(wv, __builtin_amdgcn_cvt_f32_fp8((int)qa, 3), o2);
            if (on) {
              const unsigned qb = gridB[wi];
              e0 = fmaf(wv, __builtin_amdgcn_cvt_f32_fp8((int)qb, 0), e0);
              e1 = fmaf(wv, __builtin_amdgcn_cvt_f32_fp8((int)qb, 1), e1);
              e2 = fmaf(wv, __builtin_amdgcn_cvt_f32_fp8((int)qb, 2), e2);
            }
          }
        }

        // p = (1+e^x)^-0.5 == exp(-softplus(x)*0.5) exactly; masked -> 1
        float p = 1.0f;
        if (active && !masked) {
          const float ex = fexp(dsum + kActShift);
          p = fmaxf(__builtin_amdgcn_rsqf(1.0f + ex), 1e-10f);
        }
        const float alpha = 1.0f - p;

        float incl = p;
        #pragma unroll
        for (int o = 1; o < 64; o <<= 1) {
          const float n = __shfl_up(incl, o, 64);
          if (lane >= o) incl *= n;
        }
        float excl = __shfl_up(incl, 1, 64);
        if (lane == 0) excl = 1.0f;
        const float ainv_prev = carry * excl;
        const float ainv_next = carry * incl;
        const float wgt = alpha * ainv_prev;
        carry *= __shfl(incl, 63, 64);

        float rr = sigmoidf_(o0);
        float gg = sigmoidf_(o1);
        float bb = sigmoidf_(o2);
        if (on) {
          rr += sigmoidf_(e0);
          gg += sigmoidf_(e1);
          bb += sigmoidf_(e2);
        }

        if (active) {
          __builtin_nontemporal_store(ainv_next,
              out_ainv + (size_t)ray * (kS + 1) + s + 1);
          __builtin_nontemporal_store(wgt, out_w + (size_t)ray * kS + s);
          const size_t rb = ((size_t)ray * kS + s) * 3;
          nfloat2 rg;
          rg.x = rr; rg.y = gg;
          __builtin_nontemporal_store(rg, (nfloat2*)(out_rgb + rb));
          __builtin_nontemporal_store(bb, out_rgb + rb + 2);
          accr = fmaf(wgt, rr, accr);
          accg = fmaf(wgt, gg, accg);
          accb = fmaf(wgt, bb, accb);
        }
        continue;  // live chunk handled
      }
    }

    // dead tail: alpha=0, p=1, sampler output 0 -> rgb consts
    if (active) {
      __builtin_nontemporal_store(carry,
          out_ainv + (size_t)ray * (kS + 1) + s + 1);
      __builtin_nontemporal_store(0.0f, out_w + (size_t)ray * kS + s);
      const size_t rb = ((size_t)ray * kS + s) * 3;
      nfloat2 cb;
      cb.x = c_base; cb.y = c_base;
      __builtin_nontemporal_store(cb, (nfloat2*)(out_rgb + rb));
      __builtin_nontemporal_store(c_base, out_rgb + rb + 2);
    }
  }

  #pragma unroll
  for (int o = 32; o > 0; o >>= 1) {
    accr += __shfl_xor(accr, o, 64);
    accg += __shfl_xor(accg, o, 64);
    accb += __shfl_xor(accb, o, 64);
  }
  if (lane == 0) {
    out_last[ray] = carry;
    out_rm[(size_t)ray * 3 + 0] = accr;
    out_rm[(size_t)ray * 3 + 1] = accg;
    out_rm[(size_t)ray * 3 + 2] = accb;
  }
}

extern "C" void kernel_launch(void* const* d_in, const int* in_sizes, int n_in,
                              void* d_out, int out_size, void* d_ws, size_t ws_size,
                              hipStream_t stream) {
  const float* rays_o  = (const float*)d_in[0];
  const float* rays_d  = (const float*)d_in[1];
  const float* jitter  = (const float*)d_in[2];
  const int*   em      = (const int*)d_in[3];
  const float* density = (const float*)d_in[4];
  const float* off_c   = (const float*)d_in[5];
  const float* emo_c   = (const float*)d_in[6];
  float* out = (float*)d_out;

  unsigned* gridA = (unsigned*)d_ws;          // 16.4 MB
  unsigned* gridB = gridA + kGridWords;       // 16.4 MB
  (void)ws_size;

  hipLaunchKernelGGL(repack_grids, dim3((kNB * 4 + 255) / 256), dim3(256), 0,
                     stream, density, off_c, emo_c, gridA, gridB);

  const int threads = 256;
  const int blocks  = (kR * 64) / threads;  // 2048
  hipLaunchKernelGGL(dvgo_fwd, dim3(blocks), dim3(threads), 0, stream,
                     rays_o, rays_d, jitter, em, gridA, gridB, out);
}

// Round 6
// 220.182 us; speedup vs baseline: 1.2062x; 1.0241x over previous
//
#include <hip/hip_runtime.h>
#include <math.h>

// DVGO volume-rendering forward, round 15.
// r13/r14 both died at the infra level; both contained update_dpp/readlane
// builtins never before run in this session. r15 removes ALL new builtins
// and keeps ONLY the software-pipeline change on top of the known-good r12:
//   - chunk k+1's 8 (off) / 16 (on) gathers are issued after chunk k's
//     fragments are consumed, so the scan/sigmoid/stores/next-geometry
//     (~350 cy) overlap the L2/L3 gather latency instead of exposing it
//     at a vmcnt(0) right before use.
//   - scan stays EXACTLY r12's __shfl_up Hillis-Steele (proven).
//   - unified clamp+valid gather path (border == interior, weights zeroed
//     per-corner) keeps prefetch addresses branchless.
// This isolates the serial-chain split: big win => gather latency was the
// chain; small win => the ds-shfl scan is, and next round targets it with
// mainstream constructs.
// Predicted: dvgo 56.5 -> ~40-45 us (gather-dominant) or ~50-55 (scan-
// dominant), FETCH/WRITE unchanged (53/99 MB), VALUBusy 26 -> ~33%.

namespace {
constexpr int   kR   = 8192;
constexpr int   kS   = 558;
constexpr int   kNC  = (kS + 63) / 64;            // 9 chunks
constexpr int   kG   = 160;
constexpr int   kG3  = kG * kG * kG;
constexpr float kNear = 0.05f;
constexpr float kFar  = 6.0f;
constexpr float kStepWorld = 0.5f * (2.0f / 160.0f);  // STEPSIZE * VOXEL_SIZE
constexpr float kActShift = -13.815509557963774f;     // log(1/(1-1e-6)-1)
constexpr float kLog2e = 1.4426950408889634f;
// brick layout: 2x2x4 voxels, 16 records x 4B = 64B = one cache line
constexpr int   kBX = 80, kBY = 80, kBZ = 40;
constexpr int   kNB = kBX * kBY * kBZ;            // 256000 bricks
constexpr int   kGridWords = kNB * 16;            // 16.4 MB per grid
constexpr int   kXS = kBY * kBZ * 16;             // x-brick stride in words
constexpr int   kYS = kBZ * 16;                   // y-brick stride in words
}

typedef unsigned int nuint4 __attribute__((ext_vector_type(4)));
typedef float        nfloat2 __attribute__((ext_vector_type(2)));
typedef float        nfloat4 __attribute__((ext_vector_type(4)));

__device__ __forceinline__ float fexp(float x) {   // e^x
  return __builtin_amdgcn_exp2f(x * kLog2e);
}
__device__ __forceinline__ float sigmoidf_(float x) {
  return __builtin_amdgcn_rcpf(1.0f + fexp(-x));
}

// ---- repack: planar 7-channel f32 -> two bricked fp8 grids (r12, works) ----
__global__ __launch_bounds__(256) void repack_grids(
    const float* __restrict__ density,
    const float* __restrict__ off_c,
    const float* __restrict__ emo_c,
    unsigned* __restrict__ gridA,    // [kNB*16] dens|off0|off1|off2
    unsigned* __restrict__ gridB)    // [kNB*16] emo0|emo1|emo2|0
{
  const int t   = blockIdx.x * blockDim.x + threadIdx.x;
  const int bid = t >> 2;
  const int q   = t & 3;
  if (bid >= kNB) return;
  const int bz = bid % kBZ;
  const int u  = bid / kBZ;
  const int by = u % kBY;
  const int bx = u / kBY;
  const int x  = bx * 2 + (q >> 1);
  const int y  = by * 2 + (q & 1);
  const int z0 = bz * 4;
  const int vbase = (x * kG + y) * kG + z0;

  const nfloat4 d  = __builtin_nontemporal_load((const nfloat4*)(density + vbase));
  const nfloat4 f0 = __builtin_nontemporal_load((const nfloat4*)(off_c + vbase));
  const nfloat4 f1 = __builtin_nontemporal_load((const nfloat4*)(off_c + vbase + kG3));
  const nfloat4 f2 = __builtin_nontemporal_load((const nfloat4*)(off_c + vbase + 2 * kG3));
  const nfloat4 e0 = __builtin_nontemporal_load((const nfloat4*)(emo_c + vbase));
  const nfloat4 e1 = __builtin_nontemporal_load((const nfloat4*)(emo_c + vbase + kG3));
  const nfloat4 e2 = __builtin_nontemporal_load((const nfloat4*)(emo_c + vbase + 2 * kG3));

  nuint4 va, vb;
  #pragma unroll
  for (int lz = 0; lz < 4; ++lz) {
    int qa = __builtin_amdgcn_cvt_pk_fp8_f32(d[lz],  f0[lz], 0,  false);
    qa     = __builtin_amdgcn_cvt_pk_fp8_f32(f1[lz], f2[lz], qa, true);
    int qb = __builtin_amdgcn_cvt_pk_fp8_f32(e0[lz], e1[lz], 0,  false);
    qb     = __builtin_amdgcn_cvt_pk_fp8_f32(e2[lz], 0.0f,   qb, true);
    va[lz] = (unsigned)qa;
    vb[lz] = (unsigned)qb;
  }
  const size_t woff = (size_t)bid * 16 + q * 4;
  __builtin_nontemporal_store(va, (nuint4*)(gridA + woff));
  __builtin_nontemporal_store(vb, (nuint4*)(gridB + woff));
}

// ---- main: one 64-lane wave per ray, software-pipelined gathers ----
__global__ __launch_bounds__(256) void dvgo_fwd(
    const float* __restrict__ rays_o,
    const float* __restrict__ rays_d,
    const float* __restrict__ jitter,
    const int*   __restrict__ em_modes,
    const unsigned* __restrict__ gridA,
    const unsigned* __restrict__ gridB,
    float* __restrict__ out)
{
  const int tid  = blockIdx.x * blockDim.x + threadIdx.x;
  const int ray  = tid >> 6;
  const int lane = tid & 63;
  if (ray >= kR) return;

  const float ox = rays_o[ray * 3 + 0];
  const float oy = rays_o[ray * 3 + 1];
  const float oz = rays_o[ray * 3 + 2];
  const float dx = rays_d[ray * 3 + 0];
  const float dy = rays_d[ray * 3 + 1];
  const float dz = rays_d[ray * 3 + 2];
  const float jit = jitter[ray];
  const bool  on  = (em_modes[ray] == 1);

  const float vx = (dx == 0.0f) ? 1e-6f : dx;
  const float vy = (dy == 0.0f) ? 1e-6f : dy;
  const float vz = (dz == 0.0f) ? 1e-6f : dz;
  const float ivx = __builtin_amdgcn_rcpf(vx);
  const float ivy = __builtin_amdgcn_rcpf(vy);
  const float ivz = __builtin_amdgcn_rcpf(vz);
  const float rax = ( 1.0f - ox) * ivx, rbx = (-1.0f - ox) * ivx;
  const float ray_a = ( 1.0f - oy) * ivy, rby = (-1.0f - oy) * ivy;
  const float raz = ( 1.0f - oz) * ivz, rbz = (-1.0f - oz) * ivz;
  float tmin = fmaxf(fmaxf(fminf(rax, rbx), fminf(ray_a, rby)), fminf(raz, rbz));
  float tmax = fminf(fminf(fmaxf(rax, rbx), fmaxf(ray_a, rby)), fmaxf(raz, rbz));
  tmin = fminf(fmaxf(tmin, kNear), kFar);
  tmax = fminf(fmaxf(tmax, kNear), kFar);
  const bool  ray_out = (tmax <= tmin);
  const float stepc = kStepWorld *
      __builtin_amdgcn_rsqf(dx * dx + dy * dy + dz * dz);

  float* out_ainv = out;                     // [R, S+1]
  float* out_w    = out + kR * (kS + 1);     // [R, S]
  float* out_last = out_w + kR * kS;         // [R, 1]
  float* out_rgb  = out_last + kR;           // [R, S, 3]
  float* out_rm   = out_rgb + kR * kS * 3;   // [R, 3]

  const int base_ainv = ray * (kS + 1);      // int offsets (all < 2^31)
  const int base_w    = ray * kS;

  if (lane == 0)
    __builtin_nontemporal_store(1.0f, out_ainv + base_ainv);

  const float c_base = on ? 1.0f : 0.5f;  // sigma(0) (+sigma(0) if on)

  // --- geometry helpers (closed-form per chunk; no cross-chunk deps) ---
  auto geom_addr = [&](int chunk, int wi[8]) -> unsigned long long {
    const int   s  = chunk * 64 + lane;
    const bool  ac = (s < kS);
    const float t  = tmin + stepc * ((float)s + jit);
    const float px = fmaf(dx, t, ox);
    const float py = fmaf(dy, t, oy);
    const float pz = fmaf(dz, t, oz);
    const float fx = (px + 1.0f) * 0.5f * (float)(kG - 1);
    const float fy = (py + 1.0f) * 0.5f * (float)(kG - 1);
    const float fz = (pz + 1.0f) * 0.5f * (float)(kG - 1);
    const int ix = (int)floorf(fx);
    const int iy = (int)floorf(fy);
    const int iz = (int)floorf(fz);
    const bool reach = ac &&
        (ix >= -1) && (ix <= kG - 1) &&
        (iy >= -1) && (iy <= kG - 1) &&
        (iz >= -1) && (iz <= kG - 1);
    const int gx0 = min(max(ix, 0), kG - 1),     gx1 = min(max(ix + 1, 0), kG - 1);
    const int gy0 = min(max(iy, 0), kG - 1),     gy1 = min(max(iy + 1, 0), kG - 1);
    const int gz0 = min(max(iz, 0), kG - 1),     gz1 = min(max(iz + 1, 0), kG - 1);
    const int X0 = (gx0 >> 1) * kXS + (gx0 & 1) * 8;
    const int X1 = (gx1 >> 1) * kXS + (gx1 & 1) * 8;
    const int Y0 = (gy0 >> 1) * kYS + (gy0 & 1) * 4;
    const int Y1 = (gy1 >> 1) * kYS + (gy1 & 1) * 4;
    const int Z0 = (gz0 >> 2) * 16 + (gz0 & 3);
    const int Z1 = (gz1 >> 2) * 16 + (gz1 & 3);
    wi[0] = X0 + Y0 + Z0; wi[1] = X0 + Y0 + Z1;
    wi[2] = X0 + Y1 + Z0; wi[3] = X0 + Y1 + Z1;
    wi[4] = X1 + Y0 + Z0; wi[5] = X1 + Y0 + Z1;
    wi[6] = X1 + Y1 + Z0; wi[7] = X1 + Y1 + Z1;
    return __ballot(reach);
  };

  auto geom_w = [&](int chunk, float w8[8], bool& masked, bool& active) {
    const int   s  = chunk * 64 + lane;
    active = (s < kS);
    const float t  = tmin + stepc * ((float)s + jit);
    const float px = fmaf(dx, t, ox);
    const float py = fmaf(dy, t, oy);
    const float pz = fmaf(dz, t, oz);
    const bool inb = (px >= -1.0f) & (px <= 1.0f) &
                     (py >= -1.0f) & (py <= 1.0f) &
                     (pz >= -1.0f) & (pz <= 1.0f);
    masked = ray_out || !inb;
    const float fx = (px + 1.0f) * 0.5f * (float)(kG - 1);
    const float fy = (py + 1.0f) * 0.5f * (float)(kG - 1);
    const float fz = (pz + 1.0f) * 0.5f * (float)(kG - 1);
    const int ix = (int)floorf(fx);
    const int iy = (int)floorf(fy);
    const int iz = (int)floorf(fz);
    const float wx = fx - (float)ix;
    const float wy = fy - (float)iy;
    const float wz = fz - (float)iz;
    const float x0 = 1.0f - wx, y0 = 1.0f - wy, z0 = 1.0f - wz;
    const float wxy00 = x0 * y0, wxy01 = x0 * wy;
    const float wxy10 = wx * y0, wxy11 = wx * wy;
    const bool vx0 = ((unsigned)ix       < (unsigned)kG);
    const bool vx1 = ((unsigned)(ix + 1) < (unsigned)kG);
    const bool vy0 = ((unsigned)iy       < (unsigned)kG);
    const bool vy1 = ((unsigned)(iy + 1) < (unsigned)kG);
    const bool vz0 = ((unsigned)iz       < (unsigned)kG);
    const bool vz1 = ((unsigned)(iz + 1) < (unsigned)kG);
    w8[0] = (vx0 & vy0 & vz0) ? wxy00 * z0 : 0.0f;
    w8[1] = (vx0 & vy0 & vz1) ? wxy00 * wz : 0.0f;
    w8[2] = (vx0 & vy1 & vz0) ? wxy01 * z0 : 0.0f;
    w8[3] = (vx0 & vy1 & vz1) ? wxy01 * wz : 0.0f;
    w8[4] = (vx1 & vy0 & vz0) ? wxy10 * z0 : 0.0f;
    w8[5] = (vx1 & vy0 & vz1) ? wxy10 * wz : 0.0f;
    w8[6] = (vx1 & vy1 & vz0) ? wxy11 * z0 : 0.0f;
    w8[7] = (vx1 & vy1 & vz1) ? wxy11 * wz : 0.0f;
  };

  float carry = 1.0f;
  float accr = 0.0f, accg = 0.0f, accb = 0.0f;

  unsigned ua[8] = {0, 0, 0, 0, 0, 0, 0, 0};
  unsigned ub[8] = {0, 0, 0, 0, 0, 0, 0, 0};
  bool dead_pipe = false;   // no further chunk can be live (monotone)
  bool cur_dead  = true;    // chunk about to be consumed has no reach

  { // prologue: prefetch chunk 0
    int wi[8];
    const unsigned long long bal = geom_addr(0, wi);
    if (bal == 0ull) {
      dead_pipe = true;
    } else {
      cur_dead = false;
      #pragma unroll
      for (int c = 0; c < 8; ++c) ua[c] = gridA[wi[c]];
      if (on) {
        #pragma unroll
        for (int c = 0; c < 8; ++c) ub[c] = gridB[wi[c]];
      }
    }
  }

  #pragma unroll 1
  for (int chunk = 0; chunk < kNC; ++chunk) {
    const int  s       = chunk * 64 + lane;
    const bool active0 = (s < kS);

    float dsum = 0.0f;
    float o0 = 0.0f, o1 = 0.0f, o2 = 0.0f;
    float e0 = 0.0f, e1 = 0.0f, e2 = 0.0f;
    bool masked = true, active = active0;

    if (!cur_dead) {
      float w8[8];
      geom_w(chunk, w8, masked, active);
      #pragma unroll
      for (int c = 0; c < 8; ++c) {
        const float w = w8[c];
        dsum = fmaf(w, __builtin_amdgcn_cvt_f32_fp8((int)ua[c], 0), dsum);
        o0   = fmaf(w, __builtin_amdgcn_cvt_f32_fp8((int)ua[c], 1), o0);
        o1   = fmaf(w, __builtin_amdgcn_cvt_f32_fp8((int)ua[c], 2), o1);
        o2   = fmaf(w, __builtin_amdgcn_cvt_f32_fp8((int)ua[c], 3), o2);
      }
      if (on) {
        #pragma unroll
        for (int c = 0; c < 8; ++c) {
          const float w = w8[c];
          e0 = fmaf(w, __builtin_amdgcn_cvt_f32_fp8((int)ub[c], 0), e0);
          e1 = fmaf(w, __builtin_amdgcn_cvt_f32_fp8((int)ub[c], 1), e1);
          e2 = fmaf(w, __builtin_amdgcn_cvt_f32_fp8((int)ub[c], 2), e2);
        }
      }
    }

    // ---- prefetch chunk+1 (loads overlap the scan/sigmoid/stores below) ----
    bool nxt_dead = true;
    if (!dead_pipe && (chunk + 1) < kNC) {
      int wi[8];
      const unsigned long long bal = geom_addr(chunk + 1, wi);
      if (bal == 0ull) {
        dead_pipe = true;
      } else {
        nxt_dead = false;
        #pragma unroll
        for (int c = 0; c < 8; ++c) ua[c] = gridA[wi[c]];
        if (on) {
          #pragma unroll
          for (int c = 0; c < 8; ++c) ub[c] = gridB[wi[c]];
        }
      }
    }

    // ---- finish consuming current chunk ----
    if (!cur_dead) {
      // p = (1+e^x)^-0.5 == exp(-softplus(x)*0.5) exactly; masked -> 1
      float p = 1.0f;
      if (active && !masked) {
        const float expx = fexp(dsum + kActShift);
        p = fmaxf(__builtin_amdgcn_rsqf(1.0f + expx), 1e-10f);
      }
      const float alpha = 1.0f - p;

      // r12's proven Hillis-Steele inclusive product-scan
      float incl = p;
      #pragma unroll
      for (int o = 1; o < 64; o <<= 1) {
        const float n = __shfl_up(incl, o, 64);
        if (lane >= o) incl *= n;
      }
      float excl = __shfl_up(incl, 1, 64);
      if (lane == 0) excl = 1.0f;

      const float ainv_prev = carry * excl;
      const float ainv_next = carry * incl;
      const float wgt = alpha * ainv_prev;
      carry *= __shfl(incl, 63, 64);

      float rr = sigmoidf_(o0);
      float gg = sigmoidf_(o1);
      float bb = sigmoidf_(o2);
      if (on) {
        rr += sigmoidf_(e0);
        gg += sigmoidf_(e1);
        bb += sigmoidf_(e2);
      }

      if (active) {
        __builtin_nontemporal_store(ainv_next, out_ainv + base_ainv + s + 1);
        __builtin_nontemporal_store(wgt, out_w + base_w + s);
        const int rb = (base_w + s) * 3;
        nfloat2 rg;
        rg.x = rr; rg.y = gg;
        __builtin_nontemporal_store(rg, (nfloat2*)(out_rgb + rb));
        __builtin_nontemporal_store(bb, out_rgb + rb + 2);
        accr = fmaf(wgt, rr, accr);
        accg = fmaf(wgt, gg, accg);
        accb = fmaf(wgt, bb, accb);
      }
    } else if (active0) {
      // dead tail: alpha=0, p=1, sampler output 0 -> rgb consts
      __builtin_nontemporal_store(carry, out_ainv + base_ainv + s + 1);
      __builtin_nontemporal_store(0.0f, out_w + base_w + s);
      const int rb = (base_w + s) * 3;
      nfloat2 cb;
      cb.x = c_base; cb.y = c_base;
      __builtin_nontemporal_store(cb, (nfloat2*)(out_rgb + rb));
      __builtin_nontemporal_store(c_base, out_rgb + rb + 2);
    }

    cur_dead = nxt_dead;
  }

  #pragma unroll
  for (int o = 32; o > 0; o >>= 1) {
    accr += __shfl_xor(accr, o, 64);
    accg += __shfl_xor(accg, o, 64);
    accb += __shfl_xor(accb, o, 64);
  }
  if (lane == 0) {
    out_last[ray] = carry;
    out_rm[ray * 3 + 0] = accr;
    out_rm[ray * 3 + 1] = accg;
    out_rm[ray * 3 + 2] = accb;
  }
}

extern "C" void kernel_launch(void* const* d_in, const int* in_sizes, int n_in,
                              void* d_out, int out_size, void* d_ws, size_t ws_size,
                              hipStream_t stream) {
  const float* rays_o  = (const float*)d_in[0];
  const float* rays_d  = (const float*)d_in[1];
  const float* jitter  = (const float*)d_in[2];
  const int*   em      = (const int*)d_in[3];
  const float* density = (const float*)d_in[4];
  const float* off_c   = (const float*)d_in[5];
  const float* emo_c   = (const float*)d_in[6];
  float* out = (float*)d_out;

  unsigned* gridA = (unsigned*)d_ws;          // 16.4 MB
  unsigned* gridB = gridA + kGridWords;       // 16.4 MB
  (void)ws_size;

  hipLaunchKernelGGL(repack_grids, dim3((kNB * 4 + 255) / 256), dim3(256), 0,
                     stream, density, off_c, emo_c, gridA, gridB);

  const int threads = 256;
  const int blocks  = (kR * 64) / threads;  // 2048
  hipLaunchKernelGGL(dvgo_fwd, dim3(blocks), dim3(threads), 0, stream,
                     rays_o, rays_d, jitter, em, gridA, gridB, out);
}